// Round 1
// 289.814 us; speedup vs baseline: 1.0101x; 1.0101x over previous
//
#include <hip/hip_runtime.h>

#define B_      8
#define DIM_    256
#define SEQ_    16384
#define K_      3
#define HID_    85          // DIM // 3
#define EPS_    1e-5f

typedef float floatx4 __attribute__((ext_vector_type(4)));

// ---------------------------------------------------------------------------
// Kernel 1: pooled[b*DIM+c] = mean over SEQ of x[b][c][:]
// One block per (b,c) row; 256 threads; float4 loads; wave+LDS reduction.
// Normal (cached) loads on purpose: pulls x into L3 for the conv's re-read.
// ---------------------------------------------------------------------------
__global__ __launch_bounds__(256, 8) void pool_kernel(const float* __restrict__ x,
                                                      float* __restrict__ pooled) {
    const int row = blockIdx.x;                       // b*DIM + c
    const floatx4* x4 = (const floatx4*)(x + (size_t)row * SEQ_);
    float s0 = 0.f, s1 = 0.f;
#pragma unroll
    for (int k = 0; k < SEQ_ / 4 / 256; k += 2) {     // 16 iters, 2 acc chains
        floatx4 a = x4[threadIdx.x + k * 256];
        floatx4 b = x4[threadIdx.x + (k + 1) * 256];
        s0 += (a.x + a.y) + (a.z + a.w);
        s1 += (b.x + b.y) + (b.z + b.w);
    }
    float s = s0 + s1;
#pragma unroll
    for (int off = 32; off > 0; off >>= 1) s += __shfl_down(s, off, 64);
    __shared__ float lds[4];
    const int lane = threadIdx.x & 63, wid = threadIdx.x >> 6;
    if (lane == 0) lds[wid] = s;
    __syncthreads();
    if (threadIdx.x == 0) {
        float t = (lds[0] + lds[1]) + (lds[2] + lds[3]);
        pooled[row] = t * (1.0f / SEQ_);
    }
}

// ---------------------------------------------------------------------------
// Kernel 2: tiny per-sample MLP. One block per sample b (8 blocks total).
//  y[b] = relu(BN(pooled[b] @ w1^T)) computed once (not 256x redundantly),
//  then thread c emits taps4[b*DIM+c] = {w0, w1, w2, bias[c]}.
// This removes the serial 2-barrier prologue from all 2048 conv blocks.
// ---------------------------------------------------------------------------
__global__ __launch_bounds__(256) void mlp_kernel(const float* __restrict__ pooled,
                                                  const float* __restrict__ w1,
                                                  const float* __restrict__ gamma,
                                                  const float* __restrict__ beta,
                                                  const float* __restrict__ mean,
                                                  const float* __restrict__ var,
                                                  const float* __restrict__ w2,
                                                  const float* __restrict__ b2,
                                                  const float* __restrict__ bias,
                                                  floatx4* __restrict__ taps) {
    const int b = blockIdx.x;                         // sample
    __shared__ float sp[DIM_];
    __shared__ float sy[HID_];
    sp[threadIdx.x] = pooled[b * DIM_ + threadIdx.x];
    __syncthreads();
    if (threadIdx.x < HID_) {
        const int h = threadIdx.x;
        const float* w1r = w1 + h * DIM_;
        float acc = 0.f;
#pragma unroll 8
        for (int cc = 0; cc < DIM_; ++cc) acc = fmaf(sp[cc], w1r[cc], acc);
        float t = (acc - mean[h]) * (gamma[h] * rsqrtf(var[h] + EPS_)) + beta[h];
        sy[h] = fmaxf(t, 0.f);
    }
    __syncthreads();
    const int c = threadIdx.x;                        // channel
    const float* w2r0 = w2 + (c * 3 + 0) * HID_;
    const float* w2r1 = w2 + (c * 3 + 1) * HID_;
    const float* w2r2 = w2 + (c * 3 + 2) * HID_;
    float t0 = b2[c * 3 + 0], t1 = b2[c * 3 + 1], t2 = b2[c * 3 + 2];
#pragma unroll 5
    for (int h = 0; h < HID_; ++h) {
        const float yv = sy[h];
        t0 = fmaf(yv, w2r0[h], t0);
        t1 = fmaf(yv, w2r1[h], t1);
        t2 = fmaf(yv, w2r2[h], t2);
    }
    floatx4 t;
    t.x = t0; t.y = t1; t.z = t2; t.w = bias[c];
    taps[b * DIM_ + c] = t;
}

// ---------------------------------------------------------------------------
// Kernel 3: pure streaming 3-tap depthwise conv. No LDS, no barriers.
//  One uniform 16B tap load per block, then float4 stream with shuffle halos
//  (2 scalar global loads per WAVE, not per lane). NT stores keep the 134 MB
//  of output from evicting x (L3-resident after pool) on its way out.
// ---------------------------------------------------------------------------
__global__ __launch_bounds__(256, 8) void conv_kernel(const float* __restrict__ x,
                                                      const floatx4* __restrict__ taps,
                                                      float* __restrict__ out) {
    const int row = blockIdx.x;                       // b*DIM + c
    const floatx4 t = taps[row];                      // block-uniform
    const float w0 = t.x, w1t = t.y, w2t = t.z, bs = t.w;

    const float* xr = x + (size_t)row * SEQ_;
    const floatx4* x4 = (const floatx4*)xr;
    floatx4* o4 = (floatx4*)(out + (size_t)row * SEQ_);
    const int lane = threadIdx.x & 63;
#pragma unroll
    for (int k = 0; k < SEQ_ / 4 / 256; ++k) {        // 16 iters
        const int j = threadIdx.x + k * 256;
        const int s0 = j * 4;
        floatx4 v = x4[j];
        // halos via shuffle: lanes are contiguous in j within a wave
        float left  = __shfl_up(v.w, 1, 64);
        float right = __shfl_down(v.x, 1, 64);
        if (lane == 0)  left  = (s0 > 0)        ? xr[s0 - 1] : 0.f;
        if (lane == 63) right = (s0 + 4 < SEQ_) ? xr[s0 + 4] : 0.f;
        floatx4 r;
        r.x = fmaf(w0, left, fmaf(w1t, v.x, w2t * v.y)) + bs;
        r.y = fmaf(w0, v.x,  fmaf(w1t, v.y, w2t * v.z)) + bs;
        r.z = fmaf(w0, v.y,  fmaf(w1t, v.z, w2t * v.w)) + bs;
        r.w = fmaf(w0, v.z,  fmaf(w1t, v.w, w2t * right)) + bs;
        __builtin_nontemporal_store(r, &o4[j]);
    }
}

// ---------------------------------------------------------------------------
extern "C" void kernel_launch(void* const* d_in, const int* in_sizes, int n_in,
                              void* d_out, int out_size, void* d_ws, size_t ws_size,
                              hipStream_t stream) {
    const float* x     = (const float*)d_in[0];
    const float* w1    = (const float*)d_in[1];
    const float* gamma = (const float*)d_in[2];
    const float* beta  = (const float*)d_in[3];
    const float* mean  = (const float*)d_in[4];
    const float* var   = (const float*)d_in[5];
    const float* w2    = (const float*)d_in[6];
    const float* b2    = (const float*)d_in[7];
    const float* bias  = (const float*)d_in[8];
    float* out = (float*)d_out;

    float* pooled = (float*)d_ws;                     // B*DIM = 2048 floats
    floatx4* taps = (floatx4*)((float*)d_ws + B_ * DIM_);  // B*DIM float4s (32 KB)

    pool_kernel<<<B_ * DIM_, 256, 0, stream>>>(x, pooled);
    mlp_kernel<<<B_, 256, 0, stream>>>(pooled, w1, gamma, beta, mean, var,
                                       w2, b2, bias, taps);
    conv_kernel<<<B_ * DIM_, 256, 0, stream>>>(x, taps, out);
}